// Round 12
// baseline (538.717 us; speedup 1.0000x reference)
//
#include <hip/hip_runtime.h>
#include <hip/hip_bf16.h>
#include <math.h>

#define B 64
#define S 2048
#define H 512
#define BS (B * S)

// workspace layout (floats)
#define QS_OFF 0                          // qs: B*H
#define SP_OFF (B * H)                    // score partials: 4 * B*S
#define TL_OFF (B * H + 4 * B * S)        // task list: [count, tasks...] ints (<= 4097)
#define PC_OFF (TL_OFF + 8192)            // pc: B*NCHUNK*H  (Wt aliases, used before pc)
#define NCHUNK 16
#define CHUNK  128                        // S / NCHUNK

typedef __attribute__((ext_vector_type(8))) short short8;
typedef __attribute__((ext_vector_type(4))) float f32x4;

static __device__ __forceinline__ short f2bf(float f) {
    union { float f; unsigned u; } x; x.f = f;
    unsigned r = x.u + 0x7fffu + ((x.u >> 16) & 1u);   // RNE
    return (short)(r >> 16);
}

static __device__ __forceinline__ float ftanh(float x) {
    x = fminf(fmaxf(x, -30.f), 30.f);
    const float e = __builtin_amdgcn_exp2f(x * 2.8853900817779268f); // e^(2x)
    return (e - 1.f) * __builtin_amdgcn_rcpf(e + 1.f);
}

static __device__ __forceinline__ short8 cvt8(float4 a, float4 b) {
    union { short8 s; __hip_bfloat162 h[4]; } u;
    u.h[0] = __float22bfloat162_rn(make_float2(a.x, a.y));
    u.h[1] = __float22bfloat162_rn(make_float2(a.z, a.w));
    u.h[2] = __float22bfloat162_rn(make_float2(b.x, b.y));
    u.h[3] = __float22bfloat162_rn(make_float2(b.z, b.w));
    return u.s;
}

#define GLL16(g_, l_) __builtin_amdgcn_global_load_lds(                        \
    (const __attribute__((address_space(1))) void*)(g_),                      \
    (__attribute__((address_space(3))) void*)(l_), 16, 0, 0)

// ---------------- kernel 1: q_scores = query @ W_s (B,H) ----------------
__global__ __launch_bounds__(512) void qs_kernel(const float* __restrict__ query,
                                                 const float* __restrict__ W_s,
                                                 float* __restrict__ qs) {
    const int b = blockIdx.x, k = threadIdx.x;
    __shared__ float q[H];
    q[k] = query[b * H + k];
    __syncthreads();
    float acc = 0.f;
#pragma unroll 8
    for (int h = 0; h < H; ++h) acc = fmaf(q[h], W_s[h * H + k], acc);
    qs[b * H + k] = acc;
}

// -------- kernel 1b: W_h -> bf16 fragment-ordered Wt --------
// layout: [step 16][cg 4][cb 8][lane 64][j 8] shorts
// element = W_h[k][col], k = step*32 + (lane>>4)*8 + j, col = cg*128 + cb*16 + (lane&15)
__global__ __launch_bounds__(256) void wt_prep(const float* __restrict__ W_h,
                                               short* __restrict__ Wt) {
    const int idx = blockIdx.x * 256 + threadIdx.x;       // 0 .. 262143
    const int j  = idx & 7;
    const int l  = (idx >> 3) & 63;
    const int cb = (idx >> 9) & 7;
    const int wc = (idx >> 12) & 3;
    const int st = idx >> 14;
    const int k   = st * 32 + (l >> 4) * 8 + j;
    const int col = wc * 128 + cb * 16 + (l & 15);
    Wt[idx] = f2bf(W_h[k * H + col]);
}

// -------- kernel 1c: compacted 32-row task list from lens --------
// tl[0] = count; tl[1+i] = (b<<16) | tt  (rows tt*32 .. tt*32+31)
__global__ __launch_bounds__(64) void task_kernel(const int* __restrict__ lens,
                                                  int* __restrict__ tl) {
    const int b = threadIdx.x;                 // 0..63, single wave
    const int cnt = (lens[b] + 31) >> 5;
    int pre = cnt;
#pragma unroll
    for (int off = 1; off < 64; off <<= 1) {
        const int up = __shfl_up(pre, off);
        if (b >= off) pre += up;
    }
    if (b == 63) tl[0] = pre;
    const int start = pre - cnt;
    for (int k = 0; k < cnt; ++k) tl[1 + start + k] = (b << 16) | k;
}

// ------- kernel 2: scores partials — B-resident LDS, compacted tasks, depth-4 pf -------
// 256 blocks (1/CU): cg = bid&3 (128-col group). B slice (512x128 bf16 = 128 KB) in LDS.
// 8 independent waves stream 32-row tasks from the compacted list (stride 512/cg).
// Depth-4 register A-prefetch ring; next task's first 4 slots issue before the tanh
// epilogue. acc[2][8]=64 AGPR + pf 64 VGPR: fits 256-reg budget (no spill).
__global__ __launch_bounds__(512, 2) void scores_mfma_kernel(const float* __restrict__ enc,
                                                             const short* __restrict__ Wt,
                                                             const float* __restrict__ v,
                                                             const float* __restrict__ qs,
                                                             const int* __restrict__ tl,
                                                             float* __restrict__ sp) {
    const int t = threadIdx.x;
    const int w = t >> 6, l = t & 63;
    const int g = l >> 4, c = l & 15;
    const int bid = blockIdx.x;
    const int cg = bid & 3, j = bid >> 2;      // j in [0,64)

    __shared__ __attribute__((aligned(16))) char Bs[131072];   // 128 KB B slice

    // issue one-time B load (L2-hot Wt): 16 x 8 KB, dest linear
    {
        const char* WtB = (const char*)Wt;
#pragma unroll
        for (int st = 0; st < 16; ++st)
            GLL16(WtB + (size_t)(st * 4 + cg) * 8192 + t * 16, Bs + st * 8192 + t * 16);
    }

    const int nt = tl[0];
    const int aoff = c * H + g * 8;            // per-lane A offset (floats)
    const int gw = j * 8 + w;                  // wave-slot in [0,512) per cg

    float4 pf[4][2][2];                        // depth-4 A prefetch ring (static idx)

#define ISSUE_SLOT(sl_, base_, st_)                                            \
    {                                                                          \
        _Pragma("unroll")                                                      \
        for (int rb = 0; rb < 2; ++rb) {                                       \
            const float* p_ = (base_) + rb * (16 * H) + (st_) * 32;            \
            pf[sl_][rb][0] = *(const float4*)(p_);                             \
            pf[sl_][rb][1] = *(const float4*)(p_ + 4);                         \
        }                                                                      \
    }

    // first task decode + 4-slot A prefetch BEFORE the barrier
    int i = gw;
    int b0 = -1, s0 = 0;
    const float* aT = nullptr;
    if (i < nt) {
        const int task = tl[1 + i];
        b0 = task >> 16;
        s0 = (task & 0xffff) << 5;
        aT = enc + ((size_t)b0 * S + s0) * H + aoff;
        ISSUE_SLOT(0, aT, 0)
        ISSUE_SLOT(1, aT, 1)
        ISSUE_SLOT(2, aT, 2)
        ISSUE_SLOT(3, aT, 3)
    }
    __syncthreads();

    float vreg[8];
#pragma unroll
    for (int cb = 0; cb < 8; ++cb) vreg[cb] = v[cg * 128 + cb * 16 + c];

    while (b0 >= 0) {
        // qs for this task (consumed only in epilogue; 16 steps of cover)
        float qreg[8];
#pragma unroll
        for (int cb = 0; cb < 8; ++cb) qreg[cb] = qs[b0 * H + cg * 128 + cb * 16 + c];

        f32x4 acc[2][8];
        const f32x4 z = {0.f, 0.f, 0.f, 0.f};
#pragma unroll
        for (int rb = 0; rb < 2; ++rb)
#pragma unroll
            for (int cb = 0; cb < 8; ++cb) acc[rb][cb] = z;

#pragma unroll
        for (int st = 0; st < 16; ++st) {
            // consume slot (waits only this slot's loads), then refill it for st+4
            const short8 af0 = cvt8(pf[st & 3][0][0], pf[st & 3][0][1]);
            const short8 af1 = cvt8(pf[st & 3][1][0], pf[st & 3][1][1]);
            if (st < 12) ISSUE_SLOT(st & 3, aT, st + 4)
            const char* bb_ = Bs + st * 8192 + l * 16;
            __builtin_amdgcn_s_setprio(1);
#pragma unroll
            for (int cb = 0; cb < 8; ++cb) {
                const short8 bf = *(const short8*)(bb_ + cb * 1024);
                acc[0][cb] = __builtin_amdgcn_mfma_f32_16x16x32_bf16(af0, bf, acc[0][cb], 0, 0, 0);
                acc[1][cb] = __builtin_amdgcn_mfma_f32_16x16x32_bf16(af1, bf, acc[1][cb], 0, 0, 0);
            }
            __builtin_amdgcn_s_setprio(0);
        }

        // decode + prefetch NEXT task before the epilogue (epilogue hides its latency)
        const int i2 = i + 512;
        int b2 = -1, s2 = 0;
        const float* aT2 = nullptr;
        if (i2 < nt) {
            const int task2 = tl[1 + i2];
            b2 = task2 >> 16;
            s2 = (task2 & 0xffff) << 5;
            aT2 = enc + ((size_t)b2 * S + s2) * H + aoff;
            ISSUE_SLOT(0, aT2, 0)
            ISSUE_SLOT(1, aT2, 1)
            ISSUE_SLOT(2, aT2, 2)
            ISSUE_SLOT(3, aT2, 3)
        }

        // epilogue: p[row] = sum_col v[col]*tanh(e+qs[col]); wave-local reduce
        float* spb = sp + (size_t)cg * BS + (size_t)b0 * S + s0;
#pragma unroll
        for (int rb = 0; rb < 2; ++rb) {
            float pr[4] = {0.f, 0.f, 0.f, 0.f};
#pragma unroll
            for (int cb = 0; cb < 8; ++cb)
#pragma unroll
                for (int r = 0; r < 4; ++r)
                    pr[r] += vreg[cb] * ftanh(acc[rb][cb][r] + qreg[cb]);
#pragma unroll
            for (int m = 1; m < 16; m <<= 1)
#pragma unroll
                for (int r = 0; r < 4; ++r)
                    pr[r] += __shfl_xor(pr[r], m);
            if (c == 0) {
#pragma unroll
                for (int r = 0; r < 4; ++r)
                    spb[rb * 16 + g * 4 + r] = pr[r];
            }
        }

        b0 = b2; s0 = s2; aT = aT2; i = i2;
    }
#undef ISSUE_SLOT
}

// ------ kernel 3: masked softmax over S (sums 4 col-group partials), write attn ------
__global__ __launch_bounds__(256) void softmax_kernel(const float* __restrict__ sp,
                                                      const int* __restrict__ lens,
                                                      float* __restrict__ attn) {
    const int b = blockIdx.x, t = threadIdx.x;
    const int len = lens[b];
    const int wave = t >> 6, lane = t & 63;
    __shared__ float red[4];

    float vals[8];
    float m = -INFINITY;
#pragma unroll
    for (int i = 0; i < 8; ++i) {
        const int s = i * 256 + t;
        if (s < len) {
            const size_t o = (size_t)b * S + s;
            vals[i] = sp[o] + sp[BS + o] + sp[2 * BS + o] + sp[3 * BS + o];
        } else vals[i] = -INFINITY;
        m = fmaxf(m, vals[i]);
    }
#pragma unroll
    for (int off = 32; off > 0; off >>= 1) m = fmaxf(m, __shfl_down(m, off));
    if (lane == 0) red[wave] = m;
    __syncthreads();
    m = fmaxf(fmaxf(red[0], red[1]), fmaxf(red[2], red[3]));
    __syncthreads();

    float e[8];
    float sum = 0.f;
#pragma unroll
    for (int i = 0; i < 8; ++i) {
        const int s = i * 256 + t;
        e[i] = (s < len) ? expf(vals[i] - m) : 0.f;
        sum += e[i];
    }
#pragma unroll
    for (int off = 32; off > 0; off >>= 1) sum += __shfl_down(sum, off);
    if (lane == 0) red[wave] = sum;
    __syncthreads();
    const float inv = 1.f / (red[0] + red[1] + red[2] + red[3]);
#pragma unroll
    for (int i = 0; i < 8; ++i) attn[b * S + i * 256 + t] = e[i] * inv;
}

// -------- kernel 4a: partial context sums over s-chunks (masked skipped) --------
__global__ __launch_bounds__(256) void ctx_partial_kernel(const float* __restrict__ enc,
                                                          const float* __restrict__ attn,
                                                          const int* __restrict__ lens,
                                                          float* __restrict__ pc) {
    const int b = blockIdx.x >> 4, ch = blockIdx.x & 15;
    const int len = lens[b];
    const int sbase = ch * CHUNK;
    if (sbase >= len) return;
    const int ns = min(CHUNK, len - sbase);
    const int t = threadIdx.x;

    __shared__ float alds[CHUNK];
    if (t < CHUNK) alds[t] = (t < ns) ? attn[b * S + sbase + t] : 0.f;
    __syncthreads();

    const float2* e2 = (const float2*)(enc + (size_t)(b * S + sbase) * H);
    float2 acc = make_float2(0.f, 0.f);
    for (int s = 0; s < ns; ++s) {
        const float a = alds[s];
        const float2 e = e2[s * 256 + t];
        acc.x = fmaf(a, e.x, acc.x);
        acc.y = fmaf(a, e.y, acc.y);
    }
    ((float2*)(pc + (size_t)(b * NCHUNK + ch) * H))[t] = acc;
}

// ------ kernel 4b: context reduce + w_out = tanh([ctx, q] @ W_out) ------
__global__ __launch_bounds__(512) void out_kernel(const float* __restrict__ pc,
                                                  const float* __restrict__ query,
                                                  const float* __restrict__ W_out,
                                                  const int* __restrict__ lens,
                                                  float* __restrict__ wout) {
    const int b = blockIdx.x, k = threadIdx.x;
    const int len = lens[b];
    const int nch = (len + CHUNK - 1) / CHUNK;
    __shared__ float cat[2 * H];
    float ctx = 0.f;
    for (int ch = 0; ch < nch; ++ch) ctx += pc[(size_t)(b * NCHUNK + ch) * H + k];
    cat[k] = ctx;
    cat[H + k] = query[b * H + k];
    __syncthreads();
    float acc = 0.f;
#pragma unroll 8
    for (int cI = 0; cI < 2 * H; ++cI) acc = fmaf(cat[cI], W_out[cI * H + k], acc);
    wout[b * H + k] = tanhf(acc);
}

extern "C" void kernel_launch(void* const* d_in, const int* in_sizes, int n_in,
                              void* d_out, int out_size, void* d_ws, size_t ws_size,
                              hipStream_t stream) {
    const float* query = (const float*)d_in[0];
    const float* enc   = (const float*)d_in[1];
    const int*   lens  = (const int*)d_in[2];
    const float* W_h   = (const float*)d_in[3];
    const float* W_s   = (const float*)d_in[4];
    const float* v     = (const float*)d_in[5];
    const float* W_out = (const float*)d_in[6];

    float* out  = (float*)d_out;
    float* wout = out;          // B*H
    float* attn = out + B * H;  // B*S

    float* ws = (float*)d_ws;
    float* qs = ws + QS_OFF;
    float* sp = ws + SP_OFF;
    int*   tl = (int*)(ws + TL_OFF);
    float* pc = ws + PC_OFF;
    short* Wt = (short*)(ws + PC_OFF);   // aliases pc: Wt read in scores (before pc written)

    qs_kernel<<<B, H, 0, stream>>>(query, W_s, qs);
    wt_prep<<<1024, 256, 0, stream>>>(W_h, Wt);
    task_kernel<<<1, 64, 0, stream>>>(lens, tl);
    scores_mfma_kernel<<<256, 512, 0, stream>>>(enc, Wt, v, qs, tl, sp);
    softmax_kernel<<<B, 256, 0, stream>>>(sp, lens, attn);
    ctx_partial_kernel<<<B * NCHUNK, 256, 0, stream>>>(enc, attn, lens, pc);
    out_kernel<<<B, H, 0, stream>>>(pc, query, W_out, lens, wout);
}

// Round 13
// 441.112 us; speedup vs baseline: 1.2213x; 1.2213x over previous
//
#include <hip/hip_runtime.h>
#include <hip/hip_bf16.h>
#include <math.h>

#define B 64
#define S 2048
#define H 512
#define BS (B * S)

// workspace layout (floats)
#define QS_OFF 0                          // qs: B*H
#define SP_OFF (B * H)                    // score partials: 4 * B*S
#define TL_OFF (B * H + 4 * B * S)        // task list: [count, tasks...] ints (<= 4097)
#define PC_OFF (TL_OFF + 8192)            // pc: B*NCHUNK*H  (Wt aliases, used before pc)
#define NCHUNK 16
#define CHUNK  128                        // S / NCHUNK

typedef __attribute__((ext_vector_type(8))) short short8;
typedef __attribute__((ext_vector_type(4))) float f32x4;

static __device__ __forceinline__ short f2bf(float f) {
    union { float f; unsigned u; } x; x.f = f;
    unsigned r = x.u + 0x7fffu + ((x.u >> 16) & 1u);   // RNE
    return (short)(r >> 16);
}

static __device__ __forceinline__ float ftanh(float x) {
    x = fminf(fmaxf(x, -30.f), 30.f);
    const float e = __builtin_amdgcn_exp2f(x * 2.8853900817779268f); // e^(2x)
    return (e - 1.f) * __builtin_amdgcn_rcpf(e + 1.f);
}

static __device__ __forceinline__ short8 cvt8(float4 a, float4 b) {
    union { short8 s; __hip_bfloat162 h[4]; } u;
    u.h[0] = __float22bfloat162_rn(make_float2(a.x, a.y));
    u.h[1] = __float22bfloat162_rn(make_float2(a.z, a.w));
    u.h[2] = __float22bfloat162_rn(make_float2(b.x, b.y));
    u.h[3] = __float22bfloat162_rn(make_float2(b.z, b.w));
    return u.s;
}

#define GLL16(g_, l_) __builtin_amdgcn_global_load_lds(                        \
    (const __attribute__((address_space(1))) void*)(g_),                      \
    (__attribute__((address_space(3))) void*)(l_), 16, 0, 0)

// ---------------- kernel 1: q_scores = query @ W_s (B,H) ----------------
__global__ __launch_bounds__(512) void qs_kernel(const float* __restrict__ query,
                                                 const float* __restrict__ W_s,
                                                 float* __restrict__ qs) {
    const int b = blockIdx.x, k = threadIdx.x;
    __shared__ float q[H];
    q[k] = query[b * H + k];
    __syncthreads();
    float acc = 0.f;
#pragma unroll 8
    for (int h = 0; h < H; ++h) acc = fmaf(q[h], W_s[h * H + k], acc);
    qs[b * H + k] = acc;
}

// -------- kernel 1b: W_h -> bf16 fragment-ordered Wt --------
// layout: [step 16][cg 4][cb 8][lane 64][j 8] shorts
// element = W_h[k][col], k = step*32 + (lane>>4)*8 + j, col = cg*128 + cb*16 + (lane&15)
__global__ __launch_bounds__(256) void wt_prep(const float* __restrict__ W_h,
                                               short* __restrict__ Wt) {
    const int idx = blockIdx.x * 256 + threadIdx.x;       // 0 .. 262143
    const int j  = idx & 7;
    const int l  = (idx >> 3) & 63;
    const int cb = (idx >> 9) & 7;
    const int wc = (idx >> 12) & 3;
    const int st = idx >> 14;
    const int k   = st * 32 + (l >> 4) * 8 + j;
    const int col = wc * 128 + cb * 16 + (l & 15);
    Wt[idx] = f2bf(W_h[k * H + col]);
}

// -------- kernel 1c: compacted 32-row task list from lens --------
// tl[0] = count; tl[1+i] = (b<<16) | tt  (rows tt*32 .. tt*32+31)
__global__ __launch_bounds__(64) void task_kernel(const int* __restrict__ lens,
                                                  int* __restrict__ tl) {
    const int b = threadIdx.x;                 // 0..63, single wave
    const int cnt = (lens[b] + 31) >> 5;
    int pre = cnt;
#pragma unroll
    for (int off = 1; off < 64; off <<= 1) {
        const int up = __shfl_up(pre, off);
        if (b >= off) pre += up;
    }
    if (b == 63) tl[0] = pre;
    const int start = pre - cnt;
    for (int k = 0; k < cnt; ++k) tl[1 + start + k] = (b << 16) | k;
}

// ------- kernel 2: scores partials — B-resident LDS, compacted tasks (r10 core) -------
// 256 blocks (1/CU): cg = bid>>6 (128-col group), j = bid&63. The 4 blocks sharing a
// task set (j, j+64, j+128, j+192) land on the SAME XCD (64 = 0 mod 8) -> L2-shared enc.
// B slice (512x128 bf16 = 128 KB) in LDS once. 8 independent waves, each streams ~4
// alive 32-row tasks (stride 512). Per task: cold depth-2 pf fill + 16 k-steps.
// Register pressure IDENTICAL to the no-spill r10 kernel (pf 32 + acc 64).
__global__ __launch_bounds__(512, 2) void scores_mfma_kernel(const float* __restrict__ enc,
                                                             const short* __restrict__ Wt,
                                                             const float* __restrict__ v,
                                                             const float* __restrict__ qs,
                                                             const int* __restrict__ tl,
                                                             float* __restrict__ sp) {
    const int t = threadIdx.x;
    const int w = t >> 6, l = t & 63;
    const int g = l >> 4, c = l & 15;
    const int bid = blockIdx.x;
    const int cg = bid >> 6, j = bid & 63;

    __shared__ __attribute__((aligned(16))) char Bs[131072];   // 128 KB B slice

    // one-time B load (L2-hot Wt): 16 x 8 KB, dest linear
    {
        const char* WtB = (const char*)Wt;
#pragma unroll
        for (int st = 0; st < 16; ++st)
            GLL16(WtB + (size_t)(st * 4 + cg) * 8192 + t * 16, Bs + st * 8192 + t * 16);
    }
    __syncthreads();

    const int nt = tl[0];
    const int aoff = c * H + g * 8;            // per-lane A offset (floats)
    const int gw = j * 8 + w;                  // wave-slot in [0,512) per cg

    float vreg[8];
#pragma unroll
    for (int cb = 0; cb < 8; ++cb) vreg[cb] = v[cg * 128 + cb * 16 + c];

    for (int i = gw; i < nt; i += 512) {
        const int task = tl[1 + i];
        const int b0 = task >> 16;
        const int s0 = (task & 0xffff) << 5;

        float qreg[8];
#pragma unroll
        for (int cb = 0; cb < 8; ++cb) qreg[cb] = qs[b0 * H + cg * 128 + cb * 16 + c];

        const float* aT = enc + ((size_t)b0 * S + s0) * H + aoff;

        // depth-2 A prefetch (static indexing only — r10 pattern, no spill)
        float4 pf[2][2][2];
#pragma unroll
        for (int rb = 0; rb < 2; ++rb) {
            const float* p0 = aT + rb * (16 * H);
            pf[0][rb][0] = *(const float4*)(p0);
            pf[0][rb][1] = *(const float4*)(p0 + 4);
            pf[1][rb][0] = *(const float4*)(p0 + 32);
            pf[1][rb][1] = *(const float4*)(p0 + 36);
        }

        f32x4 acc[2][8];
        const f32x4 z = {0.f, 0.f, 0.f, 0.f};
#pragma unroll
        for (int rb = 0; rb < 2; ++rb)
#pragma unroll
            for (int cb = 0; cb < 8; ++cb) acc[rb][cb] = z;

#pragma unroll
        for (int st = 0; st < 16; ++st) {
            const short8 af0 = cvt8(pf[st & 1][0][0], pf[st & 1][0][1]);
            const short8 af1 = cvt8(pf[st & 1][1][0], pf[st & 1][1][1]);
            if (st < 14) {
#pragma unroll
                for (int rb = 0; rb < 2; ++rb) {
                    const float* pn = aT + rb * (16 * H) + (st + 2) * 32;
                    pf[st & 1][rb][0] = *(const float4*)(pn);
                    pf[st & 1][rb][1] = *(const float4*)(pn + 4);
                }
            }
            const char* bb_ = Bs + st * 8192 + l * 16;
#pragma unroll
            for (int cb = 0; cb < 8; ++cb) {
                const short8 bf = *(const short8*)(bb_ + cb * 1024);
                acc[0][cb] = __builtin_amdgcn_mfma_f32_16x16x32_bf16(af0, bf, acc[0][cb], 0, 0, 0);
                acc[1][cb] = __builtin_amdgcn_mfma_f32_16x16x32_bf16(af1, bf, acc[1][cb], 0, 0, 0);
            }
        }

        // epilogue: partial p[row] = sum over this cg's 128 cols of v*tanh(e+qs)
        float* spb = sp + (size_t)cg * BS + (size_t)b0 * S + s0;
#pragma unroll
        for (int rb = 0; rb < 2; ++rb) {
            float pr[4] = {0.f, 0.f, 0.f, 0.f};
#pragma unroll
            for (int cb = 0; cb < 8; ++cb)
#pragma unroll
                for (int r = 0; r < 4; ++r)
                    pr[r] += vreg[cb] * ftanh(acc[rb][cb][r] + qreg[cb]);
#pragma unroll
            for (int m = 1; m < 16; m <<= 1)
#pragma unroll
                for (int r = 0; r < 4; ++r)
                    pr[r] += __shfl_xor(pr[r], m);
            if (c == 0) {
#pragma unroll
                for (int r = 0; r < 4; ++r)
                    spb[rb * 16 + g * 4 + r] = pr[r];
            }
        }
    }
}

// ------ kernel 3: masked softmax over S (sums 4 col-group partials), write attn ------
__global__ __launch_bounds__(256) void softmax_kernel(const float* __restrict__ sp,
                                                      const int* __restrict__ lens,
                                                      float* __restrict__ attn) {
    const int b = blockIdx.x, t = threadIdx.x;
    const int len = lens[b];
    const int wave = t >> 6, lane = t & 63;
    __shared__ float red[4];

    float vals[8];
    float m = -INFINITY;
#pragma unroll
    for (int i = 0; i < 8; ++i) {
        const int s = i * 256 + t;
        if (s < len) {
            const size_t o = (size_t)b * S + s;
            vals[i] = sp[o] + sp[BS + o] + sp[2 * BS + o] + sp[3 * BS + o];
        } else vals[i] = -INFINITY;
        m = fmaxf(m, vals[i]);
    }
#pragma unroll
    for (int off = 32; off > 0; off >>= 1) m = fmaxf(m, __shfl_down(m, off));
    if (lane == 0) red[wave] = m;
    __syncthreads();
    m = fmaxf(fmaxf(red[0], red[1]), fmaxf(red[2], red[3]));
    __syncthreads();

    float e[8];
    float sum = 0.f;
#pragma unroll
    for (int i = 0; i < 8; ++i) {
        const int s = i * 256 + t;
        e[i] = (s < len) ? expf(vals[i] - m) : 0.f;
        sum += e[i];
    }
#pragma unroll
    for (int off = 32; off > 0; off >>= 1) sum += __shfl_down(sum, off);
    if (lane == 0) red[wave] = sum;
    __syncthreads();
    const float inv = 1.f / (red[0] + red[1] + red[2] + red[3]);
#pragma unroll
    for (int i = 0; i < 8; ++i) attn[b * S + i * 256 + t] = e[i] * inv;
}

// -------- kernel 4a: partial context sums over s-chunks (masked skipped) --------
__global__ __launch_bounds__(256) void ctx_partial_kernel(const float* __restrict__ enc,
                                                          const float* __restrict__ attn,
                                                          const int* __restrict__ lens,
                                                          float* __restrict__ pc) {
    const int b = blockIdx.x >> 4, ch = blockIdx.x & 15;
    const int len = lens[b];
    const int sbase = ch * CHUNK;
    if (sbase >= len) return;
    const int ns = min(CHUNK, len - sbase);
    const int t = threadIdx.x;

    __shared__ float alds[CHUNK];
    if (t < CHUNK) alds[t] = (t < ns) ? attn[b * S + sbase + t] : 0.f;
    __syncthreads();

    const float2* e2 = (const float2*)(enc + (size_t)(b * S + sbase) * H);
    float2 acc = make_float2(0.f, 0.f);
    for (int s = 0; s < ns; ++s) {
        const float a = alds[s];
        const float2 e = e2[s * 256 + t];
        acc.x = fmaf(a, e.x, acc.x);
        acc.y = fmaf(a, e.y, acc.y);
    }
    ((float2*)(pc + (size_t)(b * NCHUNK + ch) * H))[t] = acc;
}

// ------ kernel 4b: context reduce + w_out = tanh([ctx, q] @ W_out) ------
__global__ __launch_bounds__(512) void out_kernel(const float* __restrict__ pc,
                                                  const float* __restrict__ query,
                                                  const float* __restrict__ W_out,
                                                  const int* __restrict__ lens,
                                                  float* __restrict__ wout) {
    const int b = blockIdx.x, k = threadIdx.x;
    const int len = lens[b];
    const int nch = (len + CHUNK - 1) / CHUNK;
    __shared__ float cat[2 * H];
    float ctx = 0.f;
    for (int ch = 0; ch < nch; ++ch) ctx += pc[(size_t)(b * NCHUNK + ch) * H + k];
    cat[k] = ctx;
    cat[H + k] = query[b * H + k];
    __syncthreads();
    float acc = 0.f;
#pragma unroll 8
    for (int cI = 0; cI < 2 * H; ++cI) acc = fmaf(cat[cI], W_out[cI * H + k], acc);
    wout[b * H + k] = tanhf(acc);
}

extern "C" void kernel_launch(void* const* d_in, const int* in_sizes, int n_in,
                              void* d_out, int out_size, void* d_ws, size_t ws_size,
                              hipStream_t stream) {
    const float* query = (const float*)d_in[0];
    const float* enc   = (const float*)d_in[1];
    const int*   lens  = (const int*)d_in[2];
    const float* W_h   = (const float*)d_in[3];
    const float* W_s   = (const float*)d_in[4];
    const float* v     = (const float*)d_in[5];
    const float* W_out = (const float*)d_in[6];

    float* out  = (float*)d_out;
    float* wout = out;          // B*H
    float* attn = out + B * H;  // B*S

    float* ws = (float*)d_ws;
    float* qs = ws + QS_OFF;
    float* sp = ws + SP_OFF;
    int*   tl = (int*)(ws + TL_OFF);
    float* pc = ws + PC_OFF;
    short* Wt = (short*)(ws + PC_OFF);   // aliases pc: Wt read in scores (before pc written)

    qs_kernel<<<B, H, 0, stream>>>(query, W_s, qs);
    wt_prep<<<1024, 256, 0, stream>>>(W_h, Wt);
    task_kernel<<<1, 64, 0, stream>>>(lens, tl);
    scores_mfma_kernel<<<256, 512, 0, stream>>>(enc, Wt, v, qs, tl, sp);
    softmax_kernel<<<B, 256, 0, stream>>>(sp, lens, attn);
    ctx_partial_kernel<<<B * NCHUNK, 256, 0, stream>>>(enc, attn, lens, pc);
    out_kernel<<<B, H, 0, stream>>>(pc, query, W_out, lens, wout);
}

// Round 14
// 195.044 us; speedup vs baseline: 2.7620x; 2.2616x over previous
//
#include <hip/hip_runtime.h>
#include <hip/hip_bf16.h>
#include <math.h>

#define B 64
#define S 2048
#define H 512
#define BS (B * S)

// workspace layout (floats)
#define QS_OFF 0                          // qs: B*H
#define SP_OFF (B * H)                    // score partials: 4 * B*S
#define TL_OFF (B * H + 4 * B * S)        // task list: [count, tasks...] ints (<= 4097)
#define PC_OFF (TL_OFF + 8192)            // pc: B*NCHUNK*H  (Wt aliases, used before pc)
#define NCHUNK 16
#define CHUNK  128                        // S / NCHUNK

typedef __attribute__((ext_vector_type(8))) short short8;
typedef __attribute__((ext_vector_type(4))) float f32x4;

static __device__ __forceinline__ short f2bf(float f) {
    union { float f; unsigned u; } x; x.f = f;
    unsigned r = x.u + 0x7fffu + ((x.u >> 16) & 1u);   // RNE
    return (short)(r >> 16);
}

static __device__ __forceinline__ float ftanh(float x) {
    x = fminf(fmaxf(x, -30.f), 30.f);
    const float e = __builtin_amdgcn_exp2f(x * 2.8853900817779268f); // e^(2x)
    return (e - 1.f) * __builtin_amdgcn_rcpf(e + 1.f);
}

static __device__ __forceinline__ short8 cvt8(float4 a, float4 b) {
    union { short8 s; __hip_bfloat162 h[4]; } u;
    u.h[0] = __float22bfloat162_rn(make_float2(a.x, a.y));
    u.h[1] = __float22bfloat162_rn(make_float2(a.z, a.w));
    u.h[2] = __float22bfloat162_rn(make_float2(b.x, b.y));
    u.h[3] = __float22bfloat162_rn(make_float2(b.z, b.w));
    return u.s;
}

#define GLL16(g_, l_) __builtin_amdgcn_global_load_lds(                        \
    (const __attribute__((address_space(1))) void*)(g_),                      \
    (__attribute__((address_space(3))) void*)(l_), 16, 0, 0)

// ---------------- kernel 1: q_scores = query @ W_s (B,H) ----------------
__global__ __launch_bounds__(512) void qs_kernel(const float* __restrict__ query,
                                                 const float* __restrict__ W_s,
                                                 float* __restrict__ qs) {
    const int b = blockIdx.x, k = threadIdx.x;
    __shared__ float q[H];
    q[k] = query[b * H + k];
    __syncthreads();
    float acc = 0.f;
#pragma unroll 8
    for (int h = 0; h < H; ++h) acc = fmaf(q[h], W_s[h * H + k], acc);
    qs[b * H + k] = acc;
}

// -------- kernel 1b: W_h -> bf16 fragment-ordered Wt --------
// layout: [step 16][cg 4][cb 8][lane 64][j 8] shorts
// element = W_h[k][col], k = step*32 + (lane>>4)*8 + j, col = cg*128 + cb*16 + (lane&15)
__global__ __launch_bounds__(256) void wt_prep(const float* __restrict__ W_h,
                                               short* __restrict__ Wt) {
    const int idx = blockIdx.x * 256 + threadIdx.x;       // 0 .. 262143
    const int j  = idx & 7;
    const int l  = (idx >> 3) & 63;
    const int cb = (idx >> 9) & 7;
    const int wc = (idx >> 12) & 3;
    const int st = idx >> 14;
    const int k   = st * 32 + (l >> 4) * 8 + j;
    const int col = wc * 128 + cb * 16 + (l & 15);
    Wt[idx] = f2bf(W_h[k * H + col]);
}

// -------- kernel 1c: compacted 32-row task list from lens --------
// tl[0] = count; tl[1+i] = (b<<16) | tt  (rows tt*32 .. tt*32+31)
__global__ __launch_bounds__(64) void task_kernel(const int* __restrict__ lens,
                                                  int* __restrict__ tl) {
    const int b = threadIdx.x;                 // 0..63, single wave
    const int cnt = (lens[b] + 31) >> 5;
    int pre = cnt;
#pragma unroll
    for (int off = 1; off < 64; off <<= 1) {
        const int up = __shfl_up(pre, off);
        if (b >= off) pre += up;
    }
    if (b == 63) tl[0] = pre;
    const int start = pre - cnt;
    for (int k = 0; k < cnt; ++k) tl[1 + start + k] = (b << 16) | k;
}

// ------- kernel 2: scores partials — B-resident LDS, compacted tasks, UNROLLED reps -------
// 256 blocks (1/CU): cg = bid>>6 (128-col group), j = bid&63; 4 cg-blocks of a task set
// share an XCD (64 = 0 mod 8). B slice (512x128 bf16 = 128 KB) in LDS once.
// 8 independent waves; each does up to 8 GUARDED, FULLY-UNROLLED task bodies (stride 512)
// — compile-time trip count is the no-spill form (r10 evidence: runtime loops spill).
__global__ __launch_bounds__(512, 2) void scores_mfma_kernel(const float* __restrict__ enc,
                                                             const short* __restrict__ Wt,
                                                             const float* __restrict__ v,
                                                             const float* __restrict__ qs,
                                                             const int* __restrict__ tl,
                                                             float* __restrict__ sp) {
    const int t = threadIdx.x;
    const int w = t >> 6, l = t & 63;
    const int g = l >> 4, c = l & 15;
    const int bid = blockIdx.x;
    const int cg = bid >> 6, j = bid & 63;

    __shared__ __attribute__((aligned(16))) char Bs[131072];   // 128 KB B slice

    // one-time B load (L2-hot Wt): 16 x 8 KB, dest linear
    {
        const char* WtB = (const char*)Wt;
#pragma unroll
        for (int st = 0; st < 16; ++st)
            GLL16(WtB + (size_t)(st * 4 + cg) * 8192 + t * 16, Bs + st * 8192 + t * 16);
    }
    __syncthreads();

    const int nt = tl[0];
    const int aoff = c * H + g * 8;            // per-lane A offset (floats)
    const int gw = j * 8 + w;                  // wave-slot in [0,512) per cg

    float vreg[8];
#pragma unroll
    for (int cb = 0; cb < 8; ++cb) vreg[cb] = v[cg * 128 + cb * 16 + c];

#pragma unroll
    for (int rep = 0; rep < 8; ++rep) {
        const int i = gw + rep * 512;
        if (i < nt) {
            const int task = tl[1 + i];
            const int b0 = task >> 16;
            const int s0 = (task & 0xffff) << 5;

            float qreg[8];
#pragma unroll
            for (int cb = 0; cb < 8; ++cb) qreg[cb] = qs[b0 * H + cg * 128 + cb * 16 + c];

            const float* aT = enc + ((size_t)b0 * S + s0) * H + aoff;

            // depth-2 A prefetch (static indexing only — r10 pattern)
            float4 pf[2][2][2];
#pragma unroll
            for (int rb = 0; rb < 2; ++rb) {
                const float* p0 = aT + rb * (16 * H);
                pf[0][rb][0] = *(const float4*)(p0);
                pf[0][rb][1] = *(const float4*)(p0 + 4);
                pf[1][rb][0] = *(const float4*)(p0 + 32);
                pf[1][rb][1] = *(const float4*)(p0 + 36);
            }

            f32x4 acc[2][8];
            const f32x4 z = {0.f, 0.f, 0.f, 0.f};
#pragma unroll
            for (int rb = 0; rb < 2; ++rb)
#pragma unroll
                for (int cb = 0; cb < 8; ++cb) acc[rb][cb] = z;

#pragma unroll
            for (int st = 0; st < 16; ++st) {
                const short8 af0 = cvt8(pf[st & 1][0][0], pf[st & 1][0][1]);
                const short8 af1 = cvt8(pf[st & 1][1][0], pf[st & 1][1][1]);
                if (st < 14) {
#pragma unroll
                    for (int rb = 0; rb < 2; ++rb) {
                        const float* pn = aT + rb * (16 * H) + (st + 2) * 32;
                        pf[st & 1][rb][0] = *(const float4*)(pn);
                        pf[st & 1][rb][1] = *(const float4*)(pn + 4);
                    }
                }
                const char* bb_ = Bs + st * 8192 + l * 16;
#pragma unroll
                for (int cb = 0; cb < 8; ++cb) {
                    const short8 bf = *(const short8*)(bb_ + cb * 1024);
                    acc[0][cb] = __builtin_amdgcn_mfma_f32_16x16x32_bf16(af0, bf, acc[0][cb], 0, 0, 0);
                    acc[1][cb] = __builtin_amdgcn_mfma_f32_16x16x32_bf16(af1, bf, acc[1][cb], 0, 0, 0);
                }
            }

            // epilogue: partial p[row] = sum over this cg's 128 cols of v*tanh(e+qs)
            float* spb = sp + (size_t)cg * BS + (size_t)b0 * S + s0;
#pragma unroll
            for (int rb = 0; rb < 2; ++rb) {
                float pr[4] = {0.f, 0.f, 0.f, 0.f};
#pragma unroll
                for (int cb = 0; cb < 8; ++cb)
#pragma unroll
                    for (int r = 0; r < 4; ++r)
                        pr[r] += vreg[cb] * ftanh(acc[rb][cb][r] + qreg[cb]);
#pragma unroll
                for (int m = 1; m < 16; m <<= 1)
#pragma unroll
                    for (int r = 0; r < 4; ++r)
                        pr[r] += __shfl_xor(pr[r], m);
                if (c == 0) {
#pragma unroll
                    for (int r = 0; r < 4; ++r)
                        spb[rb * 16 + g * 4 + r] = pr[r];
                }
            }
        }
    }
}

// ------ kernel 3: masked softmax over S (sums 4 col-group partials), write attn ------
__global__ __launch_bounds__(256) void softmax_kernel(const float* __restrict__ sp,
                                                      const int* __restrict__ lens,
                                                      float* __restrict__ attn) {
    const int b = blockIdx.x, t = threadIdx.x;
    const int len = lens[b];
    const int wave = t >> 6, lane = t & 63;
    __shared__ float red[4];

    float vals[8];
    float m = -INFINITY;
#pragma unroll
    for (int i = 0; i < 8; ++i) {
        const int s = i * 256 + t;
        if (s < len) {
            const size_t o = (size_t)b * S + s;
            vals[i] = sp[o] + sp[BS + o] + sp[2 * BS + o] + sp[3 * BS + o];
        } else vals[i] = -INFINITY;
        m = fmaxf(m, vals[i]);
    }
#pragma unroll
    for (int off = 32; off > 0; off >>= 1) m = fmaxf(m, __shfl_down(m, off));
    if (lane == 0) red[wave] = m;
    __syncthreads();
    m = fmaxf(fmaxf(red[0], red[1]), fmaxf(red[2], red[3]));
    __syncthreads();

    float e[8];
    float sum = 0.f;
#pragma unroll
    for (int i = 0; i < 8; ++i) {
        const int s = i * 256 + t;
        e[i] = (s < len) ? expf(vals[i] - m) : 0.f;
        sum += e[i];
    }
#pragma unroll
    for (int off = 32; off > 0; off >>= 1) sum += __shfl_down(sum, off);
    if (lane == 0) red[wave] = sum;
    __syncthreads();
    const float inv = 1.f / (red[0] + red[1] + red[2] + red[3]);
#pragma unroll
    for (int i = 0; i < 8; ++i) attn[b * S + i * 256 + t] = e[i] * inv;
}

// -------- kernel 4a: partial context sums over s-chunks (masked skipped) --------
__global__ __launch_bounds__(256) void ctx_partial_kernel(const float* __restrict__ enc,
                                                          const float* __restrict__ attn,
                                                          const int* __restrict__ lens,
                                                          float* __restrict__ pc) {
    const int b = blockIdx.x >> 4, ch = blockIdx.x & 15;
    const int len = lens[b];
    const int sbase = ch * CHUNK;
    if (sbase >= len) return;
    const int ns = min(CHUNK, len - sbase);
    const int t = threadIdx.x;

    __shared__ float alds[CHUNK];
    if (t < CHUNK) alds[t] = (t < ns) ? attn[b * S + sbase + t] : 0.f;
    __syncthreads();

    const float2* e2 = (const float2*)(enc + (size_t)(b * S + sbase) * H);
    float2 acc = make_float2(0.f, 0.f);
    for (int s = 0; s < ns; ++s) {
        const float a = alds[s];
        const float2 e = e2[s * 256 + t];
        acc.x = fmaf(a, e.x, acc.x);
        acc.y = fmaf(a, e.y, acc.y);
    }
    ((float2*)(pc + (size_t)(b * NCHUNK + ch) * H))[t] = acc;
}

// ------ kernel 4b: context reduce + w_out = tanh([ctx, q] @ W_out) ------
__global__ __launch_bounds__(512) void out_kernel(const float* __restrict__ pc,
                                                  const float* __restrict__ query,
                                                  const float* __restrict__ W_out,
                                                  const int* __restrict__ lens,
                                                  float* __restrict__ wout) {
    const int b = blockIdx.x, k = threadIdx.x;
    const int len = lens[b];
    const int nch = (len + CHUNK - 1) / CHUNK;
    __shared__ float cat[2 * H];
    float ctx = 0.f;
    for (int ch = 0; ch < nch; ++ch) ctx += pc[(size_t)(b * NCHUNK + ch) * H + k];
    cat[k] = ctx;
    cat[H + k] = query[b * H + k];
    __syncthreads();
    float acc = 0.f;
#pragma unroll 8
    for (int cI = 0; cI < 2 * H; ++cI) acc = fmaf(cat[cI], W_out[cI * H + k], acc);
    wout[b * H + k] = tanhf(acc);
}

extern "C" void kernel_launch(void* const* d_in, const int* in_sizes, int n_in,
                              void* d_out, int out_size, void* d_ws, size_t ws_size,
                              hipStream_t stream) {
    const float* query = (const float*)d_in[0];
    const float* enc   = (const float*)d_in[1];
    const int*   lens  = (const int*)d_in[2];
    const float* W_h   = (const float*)d_in[3];
    const float* W_s   = (const float*)d_in[4];
    const float* v     = (const float*)d_in[5];
    const float* W_out = (const float*)d_in[6];

    float* out  = (float*)d_out;
    float* wout = out;          // B*H
    float* attn = out + B * H;  // B*S

    float* ws = (float*)d_ws;
    float* qs = ws + QS_OFF;
    float* sp = ws + SP_OFF;
    int*   tl = (int*)(ws + TL_OFF);
    float* pc = ws + PC_OFF;
    short* Wt = (short*)(ws + PC_OFF);   // aliases pc: Wt read in scores (before pc written)

    qs_kernel<<<B, H, 0, stream>>>(query, W_s, qs);
    wt_prep<<<1024, 256, 0, stream>>>(W_h, Wt);
    task_kernel<<<1, 64, 0, stream>>>(lens, tl);
    scores_mfma_kernel<<<256, 512, 0, stream>>>(enc, Wt, v, qs, tl, sp);
    softmax_kernel<<<B, 256, 0, stream>>>(sp, lens, attn);
    ctx_partial_kernel<<<B * NCHUNK, 256, 0, stream>>>(enc, attn, lens, pc);
    out_kernel<<<B, H, 0, stream>>>(pc, query, W_out, lens, wout);
}